// Round 4
// baseline (93.383 us; speedup 1.0000x reference)
//
#include <hip/hip_runtime.h>

// VectorQuantiser via f16-split MFMA, 3-term product (xh·eh + xh·el + xl·eh).
// x: [32,32,32,256] f32; row n=(b*256+c)*16+g; elem d at linear b*262144+g*16384+d*256+c.
// emb: [64][512] f32. dist = e2[k] - 2*dot (x2 dropped: argmin-invariant).
// Block: (b,g,chalf) -> 128 rows x 512 codes, 512 threads = 8 waves (2 row x 4 code).
// Wave tile 64x32, 4x2 16x16x32_f16 frags, K=192 logical via LDS address mapping.

typedef _Float16 f16;
typedef _Float16 f16x8 __attribute__((ext_vector_type(8)));
typedef float    f32x4 __attribute__((ext_vector_type(4)));

#define NELEM0 8388608
#define FLTMAX 3.402823466e38f
// ws: [0,131072) ecvt f16[512][128] ([eh(64)|el(64)] per code); [131072,133120) e2 f32[512]
#define WS_NEED 133120

__global__ void prep_kernel(const float* __restrict__ emb, f16* __restrict__ ecvt,
                            float* __restrict__ e2g) {
    const int code = blockIdx.x * 256 + threadIdx.x;   // 512 total
    f16x8 hv[8], lv[8];
    float s = 0.0f;
    #pragma unroll
    for (int d = 0; d < 64; ++d) {
        float v = emb[d * 512 + code];                 // coalesced across codes
        s = fmaf(v, v, s);
        f16 h = (f16)v;
        hv[d >> 3][d & 7] = h;
        lv[d >> 3][d & 7] = (f16)(v - (float)h);
    }
    f16* dst = ecvt + code * 128;
    #pragma unroll
    for (int j = 0; j < 8; ++j) {
        *reinterpret_cast<f16x8*>(dst + j * 8)      = hv[j];
        *reinterpret_cast<f16x8*>(dst + 64 + j * 8) = lv[j];
    }
    e2g[code] = s;
}

// LDS tiles: [row][128 f16], XOR-swizzled: f16 index = row*128 + (koff ^ ((row&7)<<3)).
__device__ __forceinline__ int swz(int row, int koff) {
    return row * 128 + (koff ^ ((row & 7) << 3));
}

template <bool USE_WS>
__global__ __launch_bounds__(512, 4)
void vq_mfma(const float* __restrict__ x, const float* __restrict__ meanp,
             const float* __restrict__ sdp, const float* __restrict__ emb,
             const f16* __restrict__ ecvt, const float* __restrict__ e2g,
             float* __restrict__ out, float* __restrict__ outIdx)
{
    __shared__ __align__(16) f16 xa[128 * 128];   // [xh(64)|xl(64)] per row
    __shared__ __align__(16) f16 es[128 * 128];   // [eh(64)|el(64)] per code (chunk)
    __shared__ float e2s[512];
    __shared__ float red_v[4][128];
    __shared__ int   red_i[4][128];
    __shared__ int   kb[128];

    const int tid  = threadIdx.x;
    const int lane = tid & 63;
    const int wid  = tid >> 6;       // 0..7
    const int wr   = wid >> 2;       // row half (64 rows)
    const int wc   = wid & 3;        // code quarter within 128-chunk (32 codes)
    const int lr   = lane & 15;
    const int lk   = lane >> 4;

    const int blk   = blockIdx.x;    // 1024 = 32 b x 16 g x 2 chalf
    const int chalf = blk & 1;
    const int g     = (blk >> 1) & 15;
    const int b     = blk >> 5;

    const float mean = meanp[0];
    const float sd   = sdp[0];
    const bool  sdz  = (sd == 0.0f);
    const float safe = sdz ? 1.0f : sd;

    const int xbase = b * 262144 + g * 16384 + chalf * 128;

    // ---- stage A: standardise + fp16 hi/lo split, swizzled LDS ----
    {
        const int c_ = tid & 127;            // row
        const int dq = tid >> 7;             // d quarter (16 each)
        const float* src = x + xbase + c_;
        #pragma unroll
        for (int jv = 0; jv < 2; ++jv) {
            f16x8 hi, lo;
            #pragma unroll
            for (int e = 0; e < 8; ++e) {
                int d = dq * 16 + jv * 8 + e;
                float v = src[d * 256];       // coalesced: lanes = consecutive c
                float s = (sdz ? 0.0f : v / safe) - mean;
                f16 h = (f16)s;
                hi[e] = h;
                lo[e] = (f16)(s - (float)h);
            }
            *reinterpret_cast<f16x8*>(&xa[swz(c_, dq * 16 + jv * 8)])      = hi;
            *reinterpret_cast<f16x8*>(&xa[swz(c_, 64 + dq * 16 + jv * 8)]) = lo;
        }
    }

    // ---- e2 into LDS ----
    if constexpr (USE_WS) {
        e2s[tid] = e2g[tid];
    } else {
        float s = 0.0f;
        for (int d = 0; d < 64; ++d) {
            float v = emb[d * 512 + tid];
            s = fmaf(v, v, s);
        }
        e2s[tid] = s;
    }

    float bestv[16];
    int   besti[16];
    #pragma unroll
    for (int s = 0; s < 16; ++s) { bestv[s] = FLTMAX; besti[s] = 0; }

    // prefetch regs for es staging (USE_WS path): 4 x 16B per thread per chunk
    const int slot = tid & 15;       // 8-f16 slot within row
    const int rb   = tid >> 4;       // 0..31 row base
    f16x8 pre[4];
    if constexpr (USE_WS) {
        #pragma unroll
        for (int i = 0; i < 4; ++i)
            pre[i] = *reinterpret_cast<const f16x8*>(
                &ecvt[(size_t)(i * 32 + rb) * 128 + slot * 8]);
    }

    for (int ch = 0; ch < 4; ++ch) {
        __syncthreads();   // protect es from previous chunk's readers

        if constexpr (USE_WS) {
            #pragma unroll
            for (int i = 0; i < 4; ++i)
                *reinterpret_cast<f16x8*>(&es[swz(i * 32 + rb, slot * 8)]) = pre[i];
            if (ch < 3) {
                #pragma unroll
                for (int i = 0; i < 4; ++i)
                    pre[i] = *reinterpret_cast<const f16x8*>(
                        &ecvt[(size_t)((ch + 1) * 128 + i * 32 + rb) * 128 + slot * 8]);
            }
        } else {
            const int cl = tid & 127;        // code within chunk
            const int dq = tid >> 7;         // d quarter
            const float* srcE = emb + ch * 128 + cl;
            #pragma unroll
            for (int jv = 0; jv < 2; ++jv) {
                f16x8 hi, lo;
                #pragma unroll
                for (int e = 0; e < 8; ++e) {
                    int d = dq * 16 + jv * 8 + e;
                    float v = srcE[d * 512];  // coalesced: lanes = consecutive codes
                    f16 h = (f16)v;
                    hi[e] = h;
                    lo[e] = (f16)(v - (float)h);
                }
                *reinterpret_cast<f16x8*>(&es[swz(cl, dq * 16 + jv * 8)])      = hi;
                *reinterpret_cast<f16x8*>(&es[swz(cl, 64 + dq * 16 + jv * 8)]) = lo;
            }
        }
        __syncthreads();

        // ---- 64x32 wave tile, 3 terms x 2 d-halves = 6 K-steps of 32 ----
        f32x4 acc[4][2];
        #pragma unroll
        for (int fi = 0; fi < 4; ++fi)
            #pragma unroll
            for (int fj = 0; fj < 2; ++fj)
                acc[fi][fj] = (f32x4){0.f, 0.f, 0.f, 0.f};

        #pragma unroll
        for (int t = 0; t < 3; ++t) {            // (ah,eh): (0,0),(0,1),(1,0)
            const int ah = (t == 2) ? 1 : 0;
            const int eh = (t == 1) ? 1 : 0;
            #pragma unroll
            for (int dh2 = 0; dh2 < 2; ++dh2) {
                const int kB = eh * 64 + dh2 * 32 + lk * 8;
                const int kA = ah * 64 + dh2 * 32 + lk * 8;
                f16x8 bf[2], af[4];
                #pragma unroll
                for (int fj = 0; fj < 2; ++fj)
                    bf[fj] = *reinterpret_cast<const f16x8*>(
                        &es[swz(wc * 32 + fj * 16 + lr, kB)]);
                #pragma unroll
                for (int fi = 0; fi < 4; ++fi)
                    af[fi] = *reinterpret_cast<const f16x8*>(
                        &xa[swz(wr * 64 + fi * 16 + lr, kA)]);
                #pragma unroll
                for (int fi = 0; fi < 4; ++fi)
                    #pragma unroll
                    for (int fj = 0; fj < 2; ++fj)
                        acc[fi][fj] = __builtin_amdgcn_mfma_f32_16x16x32_f16(
                            af[fi], bf[fj], acc[fi][fj], 0, 0, 0);
            }
        }

        // ---- distances + running argmin (ascending code order everywhere) ----
        #pragma unroll
        for (int fj = 0; fj < 2; ++fj) {
            const int codeg = ch * 128 + wc * 32 + fj * 16 + lr;
            const float e2v = e2s[codeg];
            #pragma unroll
            for (int fi = 0; fi < 4; ++fi)
                #pragma unroll
                for (int r = 0; r < 4; ++r) {
                    float vd = fmaf(-2.0f, acc[fi][fj][r], e2v);
                    const int s = fi * 4 + r;
                    if (vd < bestv[s]) { bestv[s] = vd; besti[s] = codeg; }
                }
        }
    }

    // ---- wave-internal reduce across the 16 col-lanes (same rows) ----
    #pragma unroll
    for (int s = 0; s < 16; ++s) {
        float v = bestv[s]; int i = besti[s];
        #pragma unroll
        for (int m = 1; m < 16; m <<= 1) {
            float v2 = __shfl_xor(v, m, 64);
            int   i2 = __shfl_xor(i, m, 64);
            if (v2 < v || (v2 == v && i2 < i)) { v = v2; i = i2; }
        }
        bestv[s] = v; besti[s] = i;
    }
    if (lr == 0) {
        #pragma unroll
        for (int fi = 0; fi < 4; ++fi)
            #pragma unroll
            for (int r = 0; r < 4; ++r) {
                int row = wr * 64 + fi * 16 + lk * 4 + r;   // C/D layout row
                red_v[wc][row] = bestv[fi * 4 + r];
                red_i[wc][row] = besti[fi * 4 + r];
            }
    }
    __syncthreads();
    if (tid < 128) {
        float bv = red_v[0][tid]; int bi = red_i[0][tid];
        #pragma unroll
        for (int w = 1; w < 4; ++w) {
            float v = red_v[w][tid]; int i = red_i[w][tid];
            if (v < bv || (v == bv && i < bi)) { bv = v; bi = i; }
        }
        kb[tid] = bi;
    }
    __syncthreads();

    // ---- outputs ----
    float* out_ = out + xbase;
    #pragma unroll 4
    for (int i = 0; i < 16; ++i) {
        int lin = i * 512 + tid;
        int c_  = lin & 127;
        int d   = lin >> 7;
        float q = emb[d * 512 + kb[c_]];
        out_[d * 256 + c_] = (q + mean) * sd;   // == x+(q'-x) to ~1e-7
    }
    if (tid < 128) {
        int n = (b * 256 + chalf * 128 + tid) * 16 + g;
        outIdx[n] = (float)kb[tid];
    }
}

extern "C" void kernel_launch(void* const* d_in, const int* in_sizes, int n_in,
                              void* d_out, int out_size, void* d_ws, size_t ws_size,
                              hipStream_t stream) {
    const float* x    = (const float*)d_in[0];
    const float* mean = (const float*)d_in[1];
    const float* sd   = (const float*)d_in[2];
    const float* emb  = (const float*)d_in[3];
    float* out    = (float*)d_out;
    float* outIdx = out + NELEM0;

    if (ws_size >= (size_t)WS_NEED) {
        f16*   ecvt = (f16*)d_ws;
        float* e2g  = (float*)((char*)d_ws + 131072);
        prep_kernel<<<dim3(2), dim3(256), 0, stream>>>(emb, ecvt, e2g);
        vq_mfma<true><<<dim3(1024), dim3(512), 0, stream>>>(x, mean, sd, emb, ecvt, e2g, out, outIdx);
    } else {
        vq_mfma<false><<<dim3(1024), dim3(512), 0, stream>>>(x, mean, sd, emb, nullptr, nullptr, out, outIdx);
    }
}

// Round 5
// 91.442 us; speedup vs baseline: 1.0212x; 1.0212x over previous
//
#include <hip/hip_runtime.h>

// VectorQuantiser via f16-split MFMA, 3-term product (xh·eh + xh·el + xl·eh).
// x: [32,32,32,256] f32; row n=(b*256+c)*16+g; elem d at linear b*262144+g*16384+d*256+c.
// emb: [64][512] f32. dist = e2[k] - 2*dot (x2 dropped: argmin-invariant).
// Block: (b,g,chalf) -> 128 rows x 512 codes, 512 threads = 8 waves (2 row x 4 code).
// Wave tile 64x32, 4x2 16x16x32_f16 frags, K=192 logical via LDS address mapping.
// R5: launch_bounds(512,2) — (512,4) capped VGPR at 64 and spilled to scratch
// (R4: FETCH 18->90MB, WRITE 35->178MB). Cap 256 lets compiler sit ~112, no spill.

typedef _Float16 f16;
typedef _Float16 f16x8 __attribute__((ext_vector_type(8)));
typedef float    f32x4 __attribute__((ext_vector_type(4)));

#define NELEM0 8388608
#define FLTMAX 3.402823466e38f
// ws: [0,131072) ecvt f16[512][128] ([eh(64)|el(64)] per code); [131072,133120) e2 f32[512]
#define WS_NEED 133120

__global__ void prep_kernel(const float* __restrict__ emb, f16* __restrict__ ecvt,
                            float* __restrict__ e2g) {
    const int code = blockIdx.x * 256 + threadIdx.x;   // 512 total
    f16x8 hv[8], lv[8];
    float s = 0.0f;
    #pragma unroll
    for (int d = 0; d < 64; ++d) {
        float v = emb[d * 512 + code];                 // coalesced across codes
        s = fmaf(v, v, s);
        f16 h = (f16)v;
        hv[d >> 3][d & 7] = h;
        lv[d >> 3][d & 7] = (f16)(v - (float)h);
    }
    f16* dst = ecvt + code * 128;
    #pragma unroll
    for (int j = 0; j < 8; ++j) {
        *reinterpret_cast<f16x8*>(dst + j * 8)      = hv[j];
        *reinterpret_cast<f16x8*>(dst + 64 + j * 8) = lv[j];
    }
    e2g[code] = s;
}

// LDS tiles: [row][128 f16], XOR-swizzled: f16 index = row*128 + (koff ^ ((row&7)<<3)).
__device__ __forceinline__ int swz(int row, int koff) {
    return row * 128 + (koff ^ ((row & 7) << 3));
}

template <bool USE_WS>
__global__ __launch_bounds__(512, 2)
void vq_mfma(const float* __restrict__ x, const float* __restrict__ meanp,
             const float* __restrict__ sdp, const float* __restrict__ emb,
             const f16* __restrict__ ecvt, const float* __restrict__ e2g,
             float* __restrict__ out, float* __restrict__ outIdx)
{
    __shared__ __align__(16) f16 xa[128 * 128];   // [xh(64)|xl(64)] per row
    __shared__ __align__(16) f16 es[128 * 128];   // [eh(64)|el(64)] per code (chunk)
    __shared__ float e2s[512];
    __shared__ float red_v[4][128];
    __shared__ int   red_i[4][128];
    __shared__ int   kb[128];

    const int tid  = threadIdx.x;
    const int lane = tid & 63;
    const int wid  = tid >> 6;       // 0..7
    const int wr   = wid >> 2;       // row half (64 rows)
    const int wc   = wid & 3;        // code quarter within 128-chunk (32 codes)
    const int lr   = lane & 15;
    const int lk   = lane >> 4;

    const int blk   = blockIdx.x;    // 1024 = 32 b x 16 g x 2 chalf
    const int chalf = blk & 1;
    const int g     = (blk >> 1) & 15;
    const int b     = blk >> 5;

    const float mean = meanp[0];
    const float sd   = sdp[0];
    const bool  sdz  = (sd == 0.0f);
    const float safe = sdz ? 1.0f : sd;

    const int xbase = b * 262144 + g * 16384 + chalf * 128;

    // ---- stage A: standardise + fp16 hi/lo split, swizzled LDS ----
    {
        const int c_ = tid & 127;            // row
        const int dq = tid >> 7;             // d quarter (16 each)
        const float* src = x + xbase + c_;
        #pragma unroll
        for (int jv = 0; jv < 2; ++jv) {
            f16x8 hi, lo;
            #pragma unroll
            for (int e = 0; e < 8; ++e) {
                int d = dq * 16 + jv * 8 + e;
                float v = src[d * 256];       // coalesced: lanes = consecutive c
                float s = (sdz ? 0.0f : v / safe) - mean;
                f16 h = (f16)s;
                hi[e] = h;
                lo[e] = (f16)(s - (float)h);
            }
            *reinterpret_cast<f16x8*>(&xa[swz(c_, dq * 16 + jv * 8)])      = hi;
            *reinterpret_cast<f16x8*>(&xa[swz(c_, 64 + dq * 16 + jv * 8)]) = lo;
        }
    }

    // ---- e2 into LDS ----
    if constexpr (USE_WS) {
        e2s[tid] = e2g[tid];
    } else {
        float s = 0.0f;
        for (int d = 0; d < 64; ++d) {
            float v = emb[d * 512 + tid];
            s = fmaf(v, v, s);
        }
        e2s[tid] = s;
    }

    float bestv[16];
    int   besti[16];
    #pragma unroll
    for (int s = 0; s < 16; ++s) { bestv[s] = FLTMAX; besti[s] = 0; }

    // prefetch regs for es staging (USE_WS path): 4 x 16B per thread per chunk
    const int slot = tid & 15;       // 8-f16 slot within row
    const int rb   = tid >> 4;       // 0..31 row base
    f16x8 pre[4];
    if constexpr (USE_WS) {
        #pragma unroll
        for (int i = 0; i < 4; ++i)
            pre[i] = *reinterpret_cast<const f16x8*>(
                &ecvt[(size_t)(i * 32 + rb) * 128 + slot * 8]);
    }

    for (int ch = 0; ch < 4; ++ch) {
        __syncthreads();   // protect es from previous chunk's readers

        if constexpr (USE_WS) {
            #pragma unroll
            for (int i = 0; i < 4; ++i)
                *reinterpret_cast<f16x8*>(&es[swz(i * 32 + rb, slot * 8)]) = pre[i];
            if (ch < 3) {
                #pragma unroll
                for (int i = 0; i < 4; ++i)
                    pre[i] = *reinterpret_cast<const f16x8*>(
                        &ecvt[(size_t)((ch + 1) * 128 + i * 32 + rb) * 128 + slot * 8]);
            }
        } else {
            const int cl = tid & 127;        // code within chunk
            const int dq = tid >> 7;         // d quarter
            const float* srcE = emb + ch * 128 + cl;
            #pragma unroll
            for (int jv = 0; jv < 2; ++jv) {
                f16x8 hi, lo;
                #pragma unroll
                for (int e = 0; e < 8; ++e) {
                    int d = dq * 16 + jv * 8 + e;
                    float v = srcE[d * 512];  // coalesced: lanes = consecutive codes
                    f16 h = (f16)v;
                    hi[e] = h;
                    lo[e] = (f16)(v - (float)h);
                }
                *reinterpret_cast<f16x8*>(&es[swz(cl, dq * 16 + jv * 8)])      = hi;
                *reinterpret_cast<f16x8*>(&es[swz(cl, 64 + dq * 16 + jv * 8)]) = lo;
            }
        }
        __syncthreads();

        // ---- 64x32 wave tile, 3 terms x 2 d-halves = 6 K-steps of 32 ----
        f32x4 acc[4][2];
        #pragma unroll
        for (int fi = 0; fi < 4; ++fi)
            #pragma unroll
            for (int fj = 0; fj < 2; ++fj)
                acc[fi][fj] = (f32x4){0.f, 0.f, 0.f, 0.f};

        #pragma unroll
        for (int t = 0; t < 3; ++t) {            // (ah,eh): (0,0),(0,1),(1,0)
            const int ah = (t == 2) ? 1 : 0;
            const int eh = (t == 1) ? 1 : 0;
            #pragma unroll
            for (int dh2 = 0; dh2 < 2; ++dh2) {
                const int kB = eh * 64 + dh2 * 32 + lk * 8;
                const int kA = ah * 64 + dh2 * 32 + lk * 8;
                f16x8 bf[2], af[4];
                #pragma unroll
                for (int fj = 0; fj < 2; ++fj)
                    bf[fj] = *reinterpret_cast<const f16x8*>(
                        &es[swz(wc * 32 + fj * 16 + lr, kB)]);
                #pragma unroll
                for (int fi = 0; fi < 4; ++fi)
                    af[fi] = *reinterpret_cast<const f16x8*>(
                        &xa[swz(wr * 64 + fi * 16 + lr, kA)]);
                #pragma unroll
                for (int fi = 0; fi < 4; ++fi)
                    #pragma unroll
                    for (int fj = 0; fj < 2; ++fj)
                        acc[fi][fj] = __builtin_amdgcn_mfma_f32_16x16x32_f16(
                            af[fi], bf[fj], acc[fi][fj], 0, 0, 0);
            }
        }

        // ---- distances + running argmin (ascending code order everywhere) ----
        #pragma unroll
        for (int fj = 0; fj < 2; ++fj) {
            const int codeg = ch * 128 + wc * 32 + fj * 16 + lr;
            const float e2v = e2s[codeg];
            #pragma unroll
            for (int fi = 0; fi < 4; ++fi)
                #pragma unroll
                for (int r = 0; r < 4; ++r) {
                    float vd = fmaf(-2.0f, acc[fi][fj][r], e2v);
                    const int s = fi * 4 + r;
                    if (vd < bestv[s]) { bestv[s] = vd; besti[s] = codeg; }
                }
        }
    }

    // ---- wave-internal reduce across the 16 col-lanes (same rows) ----
    #pragma unroll
    for (int s = 0; s < 16; ++s) {
        float v = bestv[s]; int i = besti[s];
        #pragma unroll
        for (int m = 1; m < 16; m <<= 1) {
            float v2 = __shfl_xor(v, m, 64);
            int   i2 = __shfl_xor(i, m, 64);
            if (v2 < v || (v2 == v && i2 < i)) { v = v2; i = i2; }
        }
        bestv[s] = v; besti[s] = i;
    }
    if (lr == 0) {
        #pragma unroll
        for (int fi = 0; fi < 4; ++fi)
            #pragma unroll
            for (int r = 0; r < 4; ++r) {
                int row = wr * 64 + fi * 16 + lk * 4 + r;   // C/D layout row
                red_v[wc][row] = bestv[fi * 4 + r];
                red_i[wc][row] = besti[fi * 4 + r];
            }
    }
    __syncthreads();
    if (tid < 128) {
        float bv = red_v[0][tid]; int bi = red_i[0][tid];
        #pragma unroll
        for (int w = 1; w < 4; ++w) {
            float v = red_v[w][tid]; int i = red_i[w][tid];
            if (v < bv || (v == bv && i < bi)) { bv = v; bi = i; }
        }
        kb[tid] = bi;
    }
    __syncthreads();

    // ---- outputs ----
    float* out_ = out + xbase;
    #pragma unroll 4
    for (int i = 0; i < 16; ++i) {
        int lin = i * 512 + tid;
        int c_  = lin & 127;
        int d   = lin >> 7;
        float q = emb[d * 512 + kb[c_]];
        out_[d * 256 + c_] = (q + mean) * sd;   // == x+(q'-x) to ~1e-7
    }
    if (tid < 128) {
        int n = (b * 256 + chalf * 128 + tid) * 16 + g;
        outIdx[n] = (float)kb[tid];
    }
}

extern "C" void kernel_launch(void* const* d_in, const int* in_sizes, int n_in,
                              void* d_out, int out_size, void* d_ws, size_t ws_size,
                              hipStream_t stream) {
    const float* x    = (const float*)d_in[0];
    const float* mean = (const float*)d_in[1];
    const float* sd   = (const float*)d_in[2];
    const float* emb  = (const float*)d_in[3];
    float* out    = (float*)d_out;
    float* outIdx = out + NELEM0;

    if (ws_size >= (size_t)WS_NEED) {
        f16*   ecvt = (f16*)d_ws;
        float* e2g  = (float*)((char*)d_ws + 131072);
        prep_kernel<<<dim3(2), dim3(256), 0, stream>>>(emb, ecvt, e2g);
        vq_mfma<true><<<dim3(1024), dim3(512), 0, stream>>>(x, mean, sd, emb, ecvt, e2g, out, outIdx);
    } else {
        vq_mfma<false><<<dim3(1024), dim3(512), 0, stream>>>(x, mean, sd, emb, nullptr, nullptr, out, outIdx);
    }
}

// Round 6
// 89.751 us; speedup vs baseline: 1.0405x; 1.0188x over previous
//
#include <hip/hip_runtime.h>

// VectorQuantiser via f16-split MFMA, 3-term product (xh·eh + xh·el + xl·eh).
// R6 structure: barrier-free main loop. prep kernel materializes the f16-split
// codebook ecvt[512][128] (128 KB, L2-resident). Main kernel: 256 thr / 4 waves,
// 128 rows per block; xa (32 KB) staged in LDS once; each wave owns 32 rows and
// streams ALL 512 codes as B-fragments directly from global (16B runs, L2 hits).
// Full per-row argmin completes within one wave (shfl reduce over 16 cols).

typedef _Float16 f16;
typedef _Float16 f16x8 __attribute__((ext_vector_type(8)));
typedef float    f32x4 __attribute__((ext_vector_type(4)));

#define NELEM0 8388608
#define FLTMAX 3.402823466e38f
// ws: [0,131072) ecvt f16[512][128] ([eh(64)|el(64)] per code); [131072,133120) e2 f32[512]
#define WS_NEED 133120

__global__ void prep_kernel(const float* __restrict__ emb, f16* __restrict__ ecvt,
                            float* __restrict__ e2g) {
    const int code = blockIdx.x * 256 + threadIdx.x;   // 512 total
    f16x8 hv[8], lv[8];
    float s = 0.0f;
    #pragma unroll
    for (int d = 0; d < 64; ++d) {
        float v = emb[d * 512 + code];                 // coalesced across codes
        s = fmaf(v, v, s);
        f16 h = (f16)v;
        hv[d >> 3][d & 7] = h;
        lv[d >> 3][d & 7] = (f16)(v - (float)h);
    }
    f16* dst = ecvt + code * 128;
    #pragma unroll
    for (int j = 0; j < 8; ++j) {
        *reinterpret_cast<f16x8*>(dst + j * 8)      = hv[j];
        *reinterpret_cast<f16x8*>(dst + 64 + j * 8) = lv[j];
    }
    e2g[code] = s;
}

// xa: [row][128 f16], XOR-swizzled: f16 index = row*128 + (koff ^ ((row&7)<<3)).
__device__ __forceinline__ int swz(int row, int koff) {
    return row * 128 + (koff ^ ((row & 7) << 3));
}

__global__ __launch_bounds__(256)
void vq_stream(const float* __restrict__ x, const float* __restrict__ meanp,
               const float* __restrict__ sdp, const float* __restrict__ emb,
               const f16* __restrict__ ecvt, const float* __restrict__ e2g,
               float* __restrict__ out, float* __restrict__ outIdx)
{
    __shared__ __align__(16) f16 xa[128 * 128];   // [xh(64)|xl(64)] per row, 32 KB
    __shared__ float e2s[512];
    __shared__ int   kb[128];

    const int tid  = threadIdx.x;
    const int lane = tid & 63;
    const int wid  = tid >> 6;       // 0..3: wave owns rows [wid*32, wid*32+32)
    const int lr   = lane & 15;
    const int lk   = lane >> 4;

    const int blk   = blockIdx.x;    // 1024 = 32 b x 16 g x 2 chalf
    const int chalf = blk & 1;
    const int g     = (blk >> 1) & 15;
    const int b     = blk >> 5;

    const float mean = meanp[0];
    const float sd   = sdp[0];
    const bool  sdz  = (sd == 0.0f);
    const float safe = sdz ? 1.0f : sd;

    const int xbase = b * 262144 + g * 16384 + chalf * 128;

    // ---- stage xa: standardise + fp16 hi/lo split, swizzled LDS (once) ----
    {
        const int c_ = tid & 127;            // row
        const int dh = tid >> 7;             // d half (32 each)
        const float* src = x + xbase + c_;
        #pragma unroll
        for (int jv = 0; jv < 4; ++jv) {
            f16x8 hi, lo;
            #pragma unroll
            for (int e = 0; e < 8; ++e) {
                int d = dh * 32 + jv * 8 + e;
                float v = src[d * 256];       // coalesced: lanes = consecutive c
                float s = (sdz ? 0.0f : v / safe) - mean;
                f16 h = (f16)s;
                hi[e] = h;
                lo[e] = (f16)(s - (float)h);
            }
            *reinterpret_cast<f16x8*>(&xa[swz(c_, dh * 32 + jv * 8)])      = hi;
            *reinterpret_cast<f16x8*>(&xa[swz(c_, 64 + dh * 32 + jv * 8)]) = lo;
        }
    }
    // ---- e2 into LDS ----
    if (tid < 256) {
        e2s[tid * 2]     = e2g[tid * 2];
        e2s[tid * 2 + 1] = e2g[tid * 2 + 1];
    }
    __syncthreads();

    // ---- A-fragments for this wave's 32 rows: [set][part(h/l)][kslice] ----
    f16x8 afr[2][2][2];
    #pragma unroll
    for (int s = 0; s < 2; ++s) {
        const int row = wid * 32 + s * 16 + lr;
        #pragma unroll
        for (int p = 0; p < 2; ++p)
            #pragma unroll
            for (int ks = 0; ks < 2; ++ks)
                afr[s][p][ks] = *reinterpret_cast<const f16x8*>(
                    &xa[swz(row, p * 64 + ks * 32 + lk * 8)]);
    }

    float bestv[8];
    int   besti[8];
    #pragma unroll
    for (int s = 0; s < 8; ++s) { bestv[s] = FLTMAX; besti[s] = 0; }

    // ---- stream all 32 code-frags from global (L2-resident), no barriers ----
    const int koffB = lk * 8;
    #pragma unroll 2
    for (int cf = 0; cf < 32; ++cf) {
        const int code = cf * 16 + lr;
        const f16* bp = ecvt + code * 128;
        const f16x8 beh0 = *reinterpret_cast<const f16x8*>(bp + koffB);
        const f16x8 beh1 = *reinterpret_cast<const f16x8*>(bp + 32 + koffB);
        const f16x8 bel0 = *reinterpret_cast<const f16x8*>(bp + 64 + koffB);
        const f16x8 bel1 = *reinterpret_cast<const f16x8*>(bp + 96 + koffB);
        const float e2v = e2s[code];

        #pragma unroll
        for (int s = 0; s < 2; ++s) {
            f32x4 acc = (f32x4){0.f, 0.f, 0.f, 0.f};
            acc = __builtin_amdgcn_mfma_f32_16x16x32_f16(afr[s][0][0], beh0, acc, 0, 0, 0);
            acc = __builtin_amdgcn_mfma_f32_16x16x32_f16(afr[s][0][1], beh1, acc, 0, 0, 0);
            acc = __builtin_amdgcn_mfma_f32_16x16x32_f16(afr[s][0][0], bel0, acc, 0, 0, 0);
            acc = __builtin_amdgcn_mfma_f32_16x16x32_f16(afr[s][0][1], bel1, acc, 0, 0, 0);
            acc = __builtin_amdgcn_mfma_f32_16x16x32_f16(afr[s][1][0], beh0, acc, 0, 0, 0);
            acc = __builtin_amdgcn_mfma_f32_16x16x32_f16(afr[s][1][1], beh1, acc, 0, 0, 0);
            #pragma unroll
            for (int r = 0; r < 4; ++r) {
                float vd = fmaf(-2.0f, acc[r], e2v);
                const int si = s * 4 + r;
                if (vd < bestv[si]) { bestv[si] = vd; besti[si] = code; }
            }
        }
    }

    // ---- reduce across the 16 code-columns (lanes differing in bits 0-3) ----
    #pragma unroll
    for (int s = 0; s < 8; ++s) {
        float v = bestv[s]; int i = besti[s];
        #pragma unroll
        for (int m = 1; m < 16; m <<= 1) {
            float v2 = __shfl_xor(v, m, 64);
            int   i2 = __shfl_xor(i, m, 64);
            if (v2 < v || (v2 == v && i2 < i)) { v = v2; i = i2; }
        }
        bestv[s] = v; besti[s] = i;
    }
    if (lr == 0) {
        #pragma unroll
        for (int s = 0; s < 2; ++s)
            #pragma unroll
            for (int r = 0; r < 4; ++r) {
                const int row = wid * 32 + s * 16 + lk * 4 + r;   // C/D layout row
                kb[row] = besti[s * 4 + r];
            }
    }
    __syncthreads();

    // ---- outputs ----
    float* out_ = out + xbase;
    #pragma unroll 4
    for (int i = 0; i < 32; ++i) {
        int lin = i * 256 + tid;
        int c_  = lin & 127;
        int d   = lin >> 7;
        float q = emb[d * 512 + kb[c_]];
        out_[d * 256 + c_] = (q + mean) * sd;   // == x+(q'-x) to ~1e-7
    }
    if (tid < 128) {
        int n = (b * 256 + chalf * 128 + tid) * 16 + g;
        outIdx[n] = (float)kb[tid];
    }
}

// ---------------- fallback (ws too small): R5 kernel, non-ws path -------------
__global__ __launch_bounds__(512, 2)
void vq_fallback(const float* __restrict__ x, const float* __restrict__ meanp,
                 const float* __restrict__ sdp, const float* __restrict__ emb,
                 float* __restrict__ out, float* __restrict__ outIdx)
{
    __shared__ __align__(16) f16 xa[128 * 128];
    __shared__ __align__(16) f16 es[128 * 128];
    __shared__ float e2s[512];
    __shared__ float red_v[4][128];
    __shared__ int   red_i[4][128];
    __shared__ int   kb[128];

    const int tid  = threadIdx.x;
    const int lane = tid & 63;
    const int wid  = tid >> 6;
    const int wr   = wid >> 2;
    const int wc   = wid & 3;
    const int lr   = lane & 15;
    const int lk   = lane >> 4;

    const int blk   = blockIdx.x;
    const int chalf = blk & 1;
    const int g     = (blk >> 1) & 15;
    const int b     = blk >> 5;

    const float mean = meanp[0];
    const float sd   = sdp[0];
    const bool  sdz  = (sd == 0.0f);
    const float safe = sdz ? 1.0f : sd;

    const int xbase = b * 262144 + g * 16384 + chalf * 128;

    {
        const int c_ = tid & 127;
        const int dq = tid >> 7;
        const float* src = x + xbase + c_;
        #pragma unroll
        for (int jv = 0; jv < 2; ++jv) {
            f16x8 hi, lo;
            #pragma unroll
            for (int e = 0; e < 8; ++e) {
                int d = dq * 16 + jv * 8 + e;
                float v = src[d * 256];
                float s = (sdz ? 0.0f : v / safe) - mean;
                f16 h = (f16)s;
                hi[e] = h;
                lo[e] = (f16)(s - (float)h);
            }
            *reinterpret_cast<f16x8*>(&xa[swz(c_, dq * 16 + jv * 8)])      = hi;
            *reinterpret_cast<f16x8*>(&xa[swz(c_, 64 + dq * 16 + jv * 8)]) = lo;
        }
    }
    {
        float s = 0.0f;
        for (int d = 0; d < 64; ++d) {
            float v = emb[d * 512 + tid];
            s = fmaf(v, v, s);
        }
        e2s[tid] = s;
    }

    float bestv[16];
    int   besti[16];
    #pragma unroll
    for (int s = 0; s < 16; ++s) { bestv[s] = FLTMAX; besti[s] = 0; }

    for (int ch = 0; ch < 4; ++ch) {
        __syncthreads();
        {
            const int cl = tid & 127;
            const int dq = tid >> 7;
            const float* srcE = emb + ch * 128 + cl;
            #pragma unroll
            for (int jv = 0; jv < 2; ++jv) {
                f16x8 hi, lo;
                #pragma unroll
                for (int e = 0; e < 8; ++e) {
                    int d = dq * 16 + jv * 8 + e;
                    float v = srcE[d * 512];
                    f16 h = (f16)v;
                    hi[e] = h;
                    lo[e] = (f16)(v - (float)h);
                }
                *reinterpret_cast<f16x8*>(&es[swz(cl, dq * 16 + jv * 8)])      = hi;
                *reinterpret_cast<f16x8*>(&es[swz(cl, 64 + dq * 16 + jv * 8)]) = lo;
            }
        }
        __syncthreads();

        f32x4 acc[4][2];
        #pragma unroll
        for (int fi = 0; fi < 4; ++fi)
            #pragma unroll
            for (int fj = 0; fj < 2; ++fj)
                acc[fi][fj] = (f32x4){0.f, 0.f, 0.f, 0.f};

        #pragma unroll
        for (int t = 0; t < 3; ++t) {
            const int ah = (t == 2) ? 1 : 0;
            const int eh = (t == 1) ? 1 : 0;
            #pragma unroll
            for (int dh2 = 0; dh2 < 2; ++dh2) {
                const int kB = eh * 64 + dh2 * 32 + lk * 8;
                const int kA = ah * 64 + dh2 * 32 + lk * 8;
                f16x8 bf[2], af[4];
                #pragma unroll
                for (int fj = 0; fj < 2; ++fj)
                    bf[fj] = *reinterpret_cast<const f16x8*>(
                        &es[swz(wc * 32 + fj * 16 + lr, kB)]);
                #pragma unroll
                for (int fi = 0; fi < 4; ++fi)
                    af[fi] = *reinterpret_cast<const f16x8*>(
                        &xa[swz(wr * 64 + fi * 16 + lr, kA)]);
                #pragma unroll
                for (int fi = 0; fi < 4; ++fi)
                    #pragma unroll
                    for (int fj = 0; fj < 2; ++fj)
                        acc[fi][fj] = __builtin_amdgcn_mfma_f32_16x16x32_f16(
                            af[fi], bf[fj], acc[fi][fj], 0, 0, 0);
            }
        }

        #pragma unroll
        for (int fj = 0; fj < 2; ++fj) {
            const int codeg = ch * 128 + wc * 32 + fj * 16 + lr;
            const float e2v = e2s[codeg];
            #pragma unroll
            for (int fi = 0; fi < 4; ++fi)
                #pragma unroll
                for (int r = 0; r < 4; ++r) {
                    float vd = fmaf(-2.0f, acc[fi][fj][r], e2v);
                    const int s = fi * 4 + r;
                    if (vd < bestv[s]) { bestv[s] = vd; besti[s] = codeg; }
                }
        }
    }

    #pragma unroll
    for (int s = 0; s < 16; ++s) {
        float v = bestv[s]; int i = besti[s];
        #pragma unroll
        for (int m = 1; m < 16; m <<= 1) {
            float v2 = __shfl_xor(v, m, 64);
            int   i2 = __shfl_xor(i, m, 64);
            if (v2 < v || (v2 == v && i2 < i)) { v = v2; i = i2; }
        }
        bestv[s] = v; besti[s] = i;
    }
    if (lr == 0) {
        #pragma unroll
        for (int fi = 0; fi < 4; ++fi)
            #pragma unroll
            for (int r = 0; r < 4; ++r) {
                int row = wr * 64 + fi * 16 + lk * 4 + r;
                red_v[wc][row] = bestv[fi * 4 + r];
                red_i[wc][row] = besti[fi * 4 + r];
            }
    }
    __syncthreads();
    if (tid < 128) {
        float bv = red_v[0][tid]; int bi = red_i[0][tid];
        #pragma unroll
        for (int w = 1; w < 4; ++w) {
            float v = red_v[w][tid]; int i = red_i[w][tid];
            if (v < bv || (v == bv && i < bi)) { bv = v; bi = i; }
        }
        kb[tid] = bi;
    }
    __syncthreads();

    float* out_ = out + xbase;
    #pragma unroll 4
    for (int i = 0; i < 16; ++i) {
        int lin = i * 512 + tid;
        int c_  = lin & 127;
        int d   = lin >> 7;
        float q = emb[d * 512 + kb[c_]];
        out_[d * 256 + c_] = (q + mean) * sd;
    }
    if (tid < 128) {
        int n = (b * 256 + chalf * 128 + tid) * 16 + g;
        outIdx[n] = (float)kb[tid];
    }
}

extern "C" void kernel_launch(void* const* d_in, const int* in_sizes, int n_in,
                              void* d_out, int out_size, void* d_ws, size_t ws_size,
                              hipStream_t stream) {
    const float* x    = (const float*)d_in[0];
    const float* mean = (const float*)d_in[1];
    const float* sd   = (const float*)d_in[2];
    const float* emb  = (const float*)d_in[3];
    float* out    = (float*)d_out;
    float* outIdx = out + NELEM0;

    if (ws_size >= (size_t)WS_NEED) {
        f16*   ecvt = (f16*)d_ws;
        float* e2g  = (float*)((char*)d_ws + 131072);
        prep_kernel<<<dim3(2), dim3(256), 0, stream>>>(emb, ecvt, e2g);
        vq_stream<<<dim3(1024), dim3(256), 0, stream>>>(x, mean, sd, emb, ecvt, e2g, out, outIdx);
    } else {
        vq_fallback<<<dim3(1024), dim3(512), 0, stream>>>(x, mean, sd, emb, out, outIdx);
    }
}